// Round 7
// baseline (189.446 us; speedup 1.0000x reference)
//
#include <hip/hip_runtime.h>
#include <hip/hip_bf16.h>

// GAT x2 (3 heads, E=2048, batch 0 only) + 2-layer GCN, log_softmax / leaky.
// Non-neighbor exp(-30) terms dropped (~1e-10 effect vs threshold 32).
// R16/R17 lessons: sweep cost is per-block (rows amortize it); adding BLOCKS
// doubles work, adding WAVES within a block does not. R4 measured phases
// latency-bound (VALUBusy 17%). R18: split-sweep-within-block for the two
// 1-block/CU kernels:
//   kB: 768 thr, wave (c, half) sweeps half the j-range, LDS combine.
//   kD: 512 thr, wave-group kh sweeps half the k-chunks, LDS combine.
// kA/kC/kE unchanged (already 8-12 waves/CU). 5 dispatches.

// ---------------------------------------------------------------------------
// kA: blocks 0..255: 4 waves x one 64x64 adj tile each -> bm + bmT words.
//     blocks 256..303: feature transform.
__global__ __launch_bounds__(256) void kA(
    const float* __restrict__ adj0, unsigned int* __restrict__ bm,
    unsigned int* __restrict__ bmT,
    const float* __restrict__ node, const float* __restrict__ uv,
    const float* __restrict__ Wt1, const float* __restrict__ at1,
    const float* __restrict__ Wt2, const float* __restrict__ at2,
    float* __restrict__ hcol, float* __restrict__ pack1, float* __restrict__ pack2) {
  int b = blockIdx.x;
  if (b < 256) {
    int lane = threadIdx.x & 63, w = threadIdx.x >> 6;
    int t = b * 4 + w;                  // 1024 tiles
    int ti = t >> 5, tj = t & 31;       // ti: row-block, tj: col-block
    int row = ti * 64 + lane;
    const float4* ar4 = (const float4*)(adj0 + (size_t)row * 2048 + tj * 64);
    unsigned int rowLo = 0, rowHi = 0, myLo = 0, myHi = 0;
#pragma unroll
    for (int it = 0; it < 16; ++it) {
      float4 v = ar4[it];
      unsigned long long m0 = __ballot(v.x == 1.0f);
      unsigned long long m1 = __ballot(v.y == 1.0f);
      unsigned long long m2 = __ballot(v.z == 1.0f);
      unsigned long long m3 = __ballot(v.w == 1.0f);
      int jb = it * 4;
      if (jb + 0 == lane) { myLo = (unsigned int)m0; myHi = (unsigned int)(m0 >> 32); }
      if (jb + 1 == lane) { myLo = (unsigned int)m1; myHi = (unsigned int)(m1 >> 32); }
      if (jb + 2 == lane) { myLo = (unsigned int)m2; myHi = (unsigned int)(m2 >> 32); }
      if (jb + 3 == lane) { myLo = (unsigned int)m3; myHi = (unsigned int)(m3 >> 32); }
      unsigned int rb = (v.x == 1.0f ? 1u : 0u) | (v.y == 1.0f ? 2u : 0u) |
                        (v.z == 1.0f ? 4u : 0u) | (v.w == 1.0f ? 8u : 0u);
      if (it < 8) rowLo |= rb << (it * 4);
      else rowHi |= rb << ((it - 8) * 4);
    }
    *(uint2*)&bm[(size_t)row * 64 + tj * 2] = make_uint2(rowLo, rowHi);
    int j = tj * 64 + lane;
    *(uint2*)&bmT[(size_t)j * 64 + ti * 2] = make_uint2(myLo, myHi);
    return;
  }
  __shared__ float sW[192];
  __shared__ float sA[12];
  int fb = b - 256;                 // 0..47
  int g = fb / 24;
  int h = (fb / 8) % 3;
  int e = (fb % 8) * 256 + threadIdx.x;
  const float* W = (g ? Wt2 : Wt1) + h * 192;
  const float* A = (g ? at2 : at1) + h * 12;
  const float* x = (g ? uv : node) + e * 32;
  if (threadIdx.x < 192) sW[threadIdx.x] = W[threadIdx.x];
  if (threadIdx.x < 12) sA[threadIdx.x] = A[threadIdx.x];
  __syncthreads();
  float xv[32];
#pragma unroll
  for (int i = 0; i < 32; ++i) xv[i] = x[i];
  float hv[6];
#pragma unroll
  for (int d = 0; d < 6; ++d) hv[d] = 0.f;
#pragma unroll
  for (int i = 0; i < 32; ++i)
#pragma unroll
    for (int d = 0; d < 6; ++d) hv[d] += xv[i] * sW[i * 6 + d];
  float e1 = 0.f, e2 = 0.f;
#pragma unroll
  for (int d = 0; d < 6; ++d) {
    e1 += hv[d] * sA[d];
    e2 += hv[d] * sA[6 + d];
  }
  int c = g * 3 + h;
#pragma unroll
  for (int d = 0; d < 6; ++d) hcol[(c * 6 + d) * 2048 + e] = hv[d];
  pack1[c * 2048 + e] = e1;
  pack1[(6 + c) * 2048 + e] = __expf(e1);
  pack1[(12 + c) * 2048 + e] = __expf(0.2f * e1);
  pack2[c * 2048 + e] = e2;
  pack2[(6 + c) * 2048 + e] = __expf(e2);
  pack2[(12 + c) * 2048 + e] = __expf(0.2f * e2);
}

// ---------------------------------------------------------------------------
// kB: rowsum over j -> crec[c][i] = {e1, p1, hs0..hs5} (hs = h/rowsum).
// 768 thr = 12 waves: wave (c, half) sweeps half the j-range (same total
// sweep work as R17's 6-wave version, 2x the TLP). LDS combine, 48-thread
// epilogue. Grid 256 x 8 rows.
__global__ __launch_bounds__(768) void kB(
    const unsigned int* __restrict__ bm, const float* __restrict__ pack1,
    const float* __restrict__ pack2, const float* __restrict__ hcol,
    float* __restrict__ crec) {
  __shared__ float sPart[12][8];
  int tid = threadIdx.x;
  int wv = tid >> 6;            // 0..11
  int c = wv >> 1;              // 0..5
  int half = wv & 1;
  int lane = tid & 63;
  int i0 = blockIdx.x * 8;
  const float4* p2_4 = (const float4*)pack2;
  float e1r[8], p1r[8], q1r[8], sum[8];
#pragma unroll
  for (int r = 0; r < 8; ++r) {
    e1r[r] = pack1[c * 2048 + i0 + r];
    p1r[r] = pack1[(6 + c) * 2048 + i0 + r];
    q1r[r] = pack1[(12 + c) * 2048 + i0 + r];
    sum[r] = 0.f;
  }
  int sh = (lane & 7) * 4;
#pragma unroll
  for (int h2 = 0; h2 < 4; ++h2) {
    int it = half * 4 + h2;
    int j4 = it * 64 + lane;  // float4 index; covers j = 4*j4 .. +3
    float4 e2 = p2_4[c * 512 + j4];
    float4 p2 = p2_4[(6 + c) * 512 + j4];
    float4 q2 = p2_4[(12 + c) * 512 + j4];
    int wbase = it * 8 + (lane >> 3);
    float abx, aby, abz, abw;
#pragma unroll
    for (int r = 0; r < 8; ++r) {
      unsigned int wd = bm[(i0 + r) * 64 + wbase] >> sh;
      { float e = e1r[r] + e2.x; bool p = e > 0.f;
        abx = (p ? p1r[r] : q1r[r]) * (p ? p2.x : q2.x); }
      { float e = e1r[r] + e2.y; bool p = e > 0.f;
        aby = (p ? p1r[r] : q1r[r]) * (p ? p2.y : q2.y); }
      { float e = e1r[r] + e2.z; bool p = e > 0.f;
        abz = (p ? p1r[r] : q1r[r]) * (p ? p2.z : q2.z); }
      { float e = e1r[r] + e2.w; bool p = e > 0.f;
        abw = (p ? p1r[r] : q1r[r]) * (p ? p2.w : q2.w); }
      float s = ((wd & 1u) ? abx : 0.f) + ((wd & 2u) ? aby : 0.f) +
                ((wd & 4u) ? abz : 0.f) + ((wd & 8u) ? abw : 0.f);
      sum[r] += s;
    }
  }
#pragma unroll
  for (int r = 0; r < 8; ++r) {
#pragma unroll
    for (int off = 32; off > 0; off >>= 1) sum[r] += __shfl_xor(sum[r], off);
  }
  if (lane == 0) {
#pragma unroll
    for (int r = 0; r < 8; ++r) sPart[wv][r] = sum[r];
  }
  __syncthreads();
  if (tid < 48) {
    int cc = tid >> 3, r = tid & 7;
    int i = i0 + r;
    float s = sPart[cc * 2][r] + sPart[cc * 2 + 1][r];
    float inv = 1.0f / s;
    float e1 = pack1[cc * 2048 + i];
    float p1 = pack1[(6 + cc) * 2048 + i];
    float h0 = hcol[(cc * 6 + 0) * 2048 + i] * inv;
    float h1 = hcol[(cc * 6 + 1) * 2048 + i] * inv;
    float h2 = hcol[(cc * 6 + 2) * 2048 + i] * inv;
    float h3 = hcol[(cc * 6 + 3) * 2048 + i] * inv;
    float h4 = hcol[(cc * 6 + 4) * 2048 + i] * inv;
    float h5 = hcol[(cc * 6 + 5) * 2048 + i] * inv;
    float4* c4 = (float4*)crec;
    c4[(size_t)(cc * 2048 + i) * 2 + 0] = make_float4(e1, p1, h0, h1);
    c4[(size_t)(cc * 2048 + i) * 2 + 1] = make_float4(h2, h3, h4, h5);
  }
}

// ---------------------------------------------------------------------------
// kC: fused attention-aggregate + GCN1 input: for a 4-wide j-tile, full-i
// sweep of hp[j,c*6+d] = sum_i w(i,j,c)*hs[i,d]; then elu and x Wg1/Wo1
// -> T[j][32]. Wave = comp c; lane L owns i = s*64+L; per-step state is 2
// float4 loads from crec, prefetched one step ahead. Grid 512 (j0 = blk*4).
__global__ __launch_bounds__(384) void kC(
    const unsigned int* __restrict__ bmT, const float* __restrict__ crec,
    const float* __restrict__ pack2,
    const float* __restrict__ Wg1, const float* __restrict__ Wo1,
    float* __restrict__ T) {
  __shared__ float sW[576];       // Wg1 (288) then Wo1 (288)
  __shared__ float sHP[4 * 37];
  int tid = threadIdx.x;
  int c = tid >> 6, L = tid & 63;
  int j0 = blockIdx.x * 4;
  if (tid < 288) { sW[tid] = Wg1[tid]; sW[288 + tid] = Wo1[tid]; }
  // per-lane mask words: wj[jj] = word L of column j0+jj (rows L*32..+31)
  int wj[4];
#pragma unroll
  for (int jj = 0; jj < 4; ++jj) wj[jj] = (int)bmT[(size_t)(j0 + jj) * 64 + L];
  // wave-uniform j-side scalars
  float e2v[4], p2v[4], q2v[4];
#pragma unroll
  for (int jj = 0; jj < 4; ++jj) {
    e2v[jj] = pack2[c * 2048 + j0 + jj];
    p2v[jj] = pack2[(6 + c) * 2048 + j0 + jj];
    q2v[jj] = pack2[(12 + c) * 2048 + j0 + jj];
  }
  float acc[4][6];
#pragma unroll
  for (int jj = 0; jj < 4; ++jj)
#pragma unroll
    for (int d = 0; d < 6; ++d) acc[jj][d] = 0.f;

  const float4* R4 = (const float4*)crec;
  int base = c * 2048 + L;
  float4 a0 = R4[(size_t)base * 2];
  float4 a1 = R4[(size_t)base * 2 + 1];
  for (int s = 0; s < 32; ++s) {
    // prefetch step s+1 ((s+1)&31 wraps -> always in-bounds, value unused)
    int nb = base + (((s + 1) & 31) << 6);
    float4 b0 = R4[(size_t)nb * 2];
    float4 b1 = R4[(size_t)nb * 2 + 1];
    float e1 = a0.x, p1 = a0.y;
    float q1 = __expf(0.2f * e1);   // bit-identical to kA's pack1[12+c]
    float h0 = a0.z, h1 = a0.w;
    float h2 = a1.x, h3 = a1.y, h4 = a1.z, h5 = a1.w;
#pragma unroll
    for (int jj = 0; jj < 4; ++jj) {
      int lo = __builtin_amdgcn_readlane(wj[jj], 2 * s);
      int hi = __builtin_amdgcn_readlane(wj[jj], 2 * s + 1);
      unsigned int wsel = (unsigned int)((L & 32) ? hi : lo);
      float e = e1 + e2v[jj];
      bool pos = e > 0.f;
      float ab = (pos ? p1 : q1) * (pos ? p2v[jj] : q2v[jj]);
      float wgt = ((wsel >> (L & 31)) & 1u) ? ab : 0.f;
      acc[jj][0] += wgt * h0; acc[jj][1] += wgt * h1; acc[jj][2] += wgt * h2;
      acc[jj][3] += wgt * h3; acc[jj][4] += wgt * h4; acc[jj][5] += wgt * h5;
    }
    a0 = b0; a1 = b1;
  }
  // butterfly: every lane ends with the full i-sum
#pragma unroll
  for (int jj = 0; jj < 4; ++jj)
#pragma unroll
    for (int d = 0; d < 6; ++d)
#pragma unroll
      for (int off = 32; off > 0; off >>= 1)
        acc[jj][d] += __shfl_xor(acc[jj][d], off);
  if (L == 0) {
#pragma unroll
    for (int jj = 0; jj < 4; ++jj)
#pragma unroll
      for (int d = 0; d < 6; ++d) {
        float x = acc[jj][d];
        sHP[jj * 37 + c * 6 + d] = x > 0.f ? x : __expf(x) - 1.f;  // elu
      }
  }
  __syncthreads();
  if (tid < 128) {
    int j = tid >> 5, col = tid & 31;
    int gat = col >> 4, cp = col & 15;
    const float* Wp = sW + gat * 288;
    const float* hp = sHP + j * 37 + gat * 18;
    float a = 0.f;
#pragma unroll
    for (int r = 0; r < 18; ++r) a += hp[r] * Wp[r * 16 + cp];
    T[(size_t)(j0 + j) * 32 + col] = a;
  }
}

// ---------------------------------------------------------------------------
// kD: fused GCN1-aggregate + GCN2 input: 8 rows per block; 512 thr = 8
// waves; wave-group kh sweeps half the k-chunks (same total sweep work,
// 2x TLP). LDS combine then relu(+bias) x Wg2/Wo2 -> T2[r][4]. Grid 256.
__global__ __launch_bounds__(512) void kD(
    const unsigned int* __restrict__ bm, const float* __restrict__ T,
    const float* __restrict__ bg1, const float* __restrict__ bo1,
    const float* __restrict__ Wg2, const float* __restrict__ Wo2,
    float* __restrict__ T2) {
  __shared__ float sC[2][8][32];
  int tid = threadIdx.x;
  int kl = tid & 31, cg = (tid >> 5) & 7, kh = tid >> 8;
  int r0 = blockIdx.x * 8;
  const float4* T4 = (const float4*)T;
  float4 acc[8];
#pragma unroll
  for (int rr = 0; rr < 8; ++rr) acc[rr] = make_float4(0.f, 0.f, 0.f, 0.f);
#pragma unroll
  for (int c2 = 0; c2 < 4; ++c2) {
    int ch = kh * 4 + c2;
    float4 tv[8];
#pragma unroll
    for (int t = 0; t < 8; ++t)
      tv[t] = T4[(size_t)(ch * 256 + t * 32 + kl) * 8 + cg];
#pragma unroll
    for (int rr = 0; rr < 8; ++rr) {
      const unsigned int* wp = &bm[(size_t)(r0 + rr) * 64 + ch * 8];
      uint4 wA = *(const uint4*)wp;
      uint4 wB = *(const uint4*)(wp + 4);
      float m;
      m = (float)((wA.x >> kl) & 1u);
      acc[rr].x += m * tv[0].x; acc[rr].y += m * tv[0].y;
      acc[rr].z += m * tv[0].z; acc[rr].w += m * tv[0].w;
      m = (float)((wA.y >> kl) & 1u);
      acc[rr].x += m * tv[1].x; acc[rr].y += m * tv[1].y;
      acc[rr].z += m * tv[1].z; acc[rr].w += m * tv[1].w;
      m = (float)((wA.z >> kl) & 1u);
      acc[rr].x += m * tv[2].x; acc[rr].y += m * tv[2].y;
      acc[rr].z += m * tv[2].z; acc[rr].w += m * tv[2].w;
      m = (float)((wA.w >> kl) & 1u);
      acc[rr].x += m * tv[3].x; acc[rr].y += m * tv[3].y;
      acc[rr].z += m * tv[3].z; acc[rr].w += m * tv[3].w;
      m = (float)((wB.x >> kl) & 1u);
      acc[rr].x += m * tv[4].x; acc[rr].y += m * tv[4].y;
      acc[rr].z += m * tv[4].z; acc[rr].w += m * tv[4].w;
      m = (float)((wB.y >> kl) & 1u);
      acc[rr].x += m * tv[5].x; acc[rr].y += m * tv[5].y;
      acc[rr].z += m * tv[5].z; acc[rr].w += m * tv[5].w;
      m = (float)((wB.z >> kl) & 1u);
      acc[rr].x += m * tv[6].x; acc[rr].y += m * tv[6].y;
      acc[rr].z += m * tv[6].z; acc[rr].w += m * tv[6].w;
      m = (float)((wB.w >> kl) & 1u);
      acc[rr].x += m * tv[7].x; acc[rr].y += m * tv[7].y;
      acc[rr].z += m * tv[7].z; acc[rr].w += m * tv[7].w;
    }
  }
#pragma unroll
  for (int rr = 0; rr < 8; ++rr) {
#pragma unroll
    for (int m = 16; m > 0; m >>= 1) {
      acc[rr].x += __shfl_xor(acc[rr].x, m);
      acc[rr].y += __shfl_xor(acc[rr].y, m);
      acc[rr].z += __shfl_xor(acc[rr].z, m);
      acc[rr].w += __shfl_xor(acc[rr].w, m);
    }
  }
  if (kl == 0) {
#pragma unroll
    for (int rr = 0; rr < 8; ++rr)
      *(float4*)&sC[kh][rr][cg * 4] = acc[rr];
  }
  __syncthreads();
  if (tid < 256) {
    int r = tid >> 5, col = tid & 31;
    int gat = col >> 4, cc = col & 15;
    float x = sC[0][r][col] + sC[1][r][col] + (gat ? bo1[cc] : bg1[cc]);
    x = x > 0.f ? x : 0.f;  // relu
    float wa = gat ? Wo2[cc * 2 + 0] : Wg2[cc * 2 + 0];
    float wb = gat ? Wo2[cc * 2 + 1] : Wg2[cc * 2 + 1];
    float pa = x * wa, pb = x * wb;
#pragma unroll
    for (int m = 8; m > 0; m >>= 1) {
      pa += __shfl_xor(pa, m);
      pb += __shfl_xor(pb, m);
    }
    if (cc == 0) {
      T2[(size_t)(r0 + r) * 4 + gat * 2 + 0] = pa;
      T2[(size_t)(r0 + r) * 4 + gat * 2 + 1] = pb;
    }
  }
}

// ---------------------------------------------------------------------------
// kE: final out = a0 @ T2 (+bias), log_softmax(axis=1) + leaky(0.01).
// Wave per row, grid 512.
__global__ __launch_bounds__(256) void kE(
    const unsigned int* __restrict__ bm, const float* __restrict__ T2,
    const float* __restrict__ bg2, const float* __restrict__ bo2,
    float* __restrict__ out) {
  int tid = threadIdx.x;
  int lane = tid & 63, w = tid >> 6;
  int r = blockIdx.x * 4 + w;
  const float4* T24 = (const float4*)T2;
  float4 acc = make_float4(0.f, 0.f, 0.f, 0.f);
  int sh = lane & 31;
#pragma unroll 8
  for (int it = 0; it < 32; ++it) {
    int k = it * 64 + lane;
    unsigned int wd = bm[r * 64 + it * 2 + (lane >> 5)];
    float m = (float)((wd >> sh) & 1u);
    float4 t = T24[k];
    acc.x += m * t.x;
    acc.y += m * t.y;
    acc.z += m * t.z;
    acc.w += m * t.w;
  }
#pragma unroll
  for (int off = 32; off > 0; off >>= 1) {
    acc.x += __shfl_down(acc.x, off);
    acc.y += __shfl_down(acc.y, off);
    acc.z += __shfl_down(acc.z, off);
    acc.w += __shfl_down(acc.w, off);
  }
  if (lane == 0) {
    float y0 = acc.x + bg2[0], y1 = acc.y + bg2[1];
    float m = fmaxf(y0, y1);
    float ls = m + logf(__expf(y0 - m) + __expf(y1 - m));
    out[r * 2 + 0] = y0 - ls;
    out[r * 2 + 1] = y1 - ls;
    float o0 = acc.z + bo2[0], o1 = acc.w + bo2[1];
    out[4096 + r * 2 + 0] = o0 > 0.f ? o0 : 0.01f * o0;
    out[4096 + r * 2 + 1] = o1 > 0.f ? o1 : 0.01f * o1;
  }
}

extern "C" void kernel_launch(void* const* d_in, const int* in_sizes, int n_in,
                              void* d_out, int out_size, void* d_ws, size_t ws_size,
                              hipStream_t stream) {
  const float* node = (const float*)d_in[0];
  const float* uv = (const float*)d_in[1];
  const float* adj = (const float*)d_in[2];  // batch 0 = first 2048*2048
  const float* Wt1 = (const float*)d_in[3];
  const float* at1 = (const float*)d_in[4];
  const float* Wt2 = (const float*)d_in[5];
  const float* at2 = (const float*)d_in[6];
  const float* Wg1 = (const float*)d_in[7];
  const float* bg1 = (const float*)d_in[8];
  const float* Wg2 = (const float*)d_in[9];
  const float* bg2 = (const float*)d_in[10];
  const float* Wo1 = (const float*)d_in[11];
  const float* bo1 = (const float*)d_in[12];
  const float* Wo2 = (const float*)d_in[13];
  const float* bo2 = (const float*)d_in[14];
  float* ws = (float*)d_ws;
  float* hcol = ws;                               // 73728
  float* pack1 = ws + 73728;                      // 36864
  float* pack2 = ws + 110592;                     // 36864
  float* crec = ws + 147456;                      // 6*2048*8 = 98304
  float* T = ws + 245760;                         // 65536
  float* T2 = ws + 311296;                        // 8192
  unsigned int* bm = (unsigned int*)(ws + 319488);   // 131072 u32 = 512 KB
  unsigned int* bmT = (unsigned int*)(ws + 450560);  // 131072 u32 = 512 KB
  float* out = (float*)d_out;

  kA<<<304, 256, 0, stream>>>(adj, bm, bmT, node, uv, Wt1, at1, Wt2, at2,
                              hcol, pack1, pack2);
  kB<<<256, 768, 0, stream>>>(bm, pack1, pack2, hcol, crec);
  kC<<<512, 384, 0, stream>>>(bmT, crec, pack2, Wg1, Wo1, T);
  kD<<<256, 512, 0, stream>>>(bm, T, bg1, bo1, Wg2, Wo2, T2);
  kE<<<512, 256, 0, stream>>>(bm, T2, bg2, bo2, out);
}

// Round 8
// 172.461 us; speedup vs baseline: 1.0985x; 1.0985x over previous
//
#include <hip/hip_runtime.h>
#include <hip/hip_bf16.h>

// GAT x2 (3 heads, E=2048, batch 0 only) + 2-layer GCN, log_softmax / leaky.
// Non-neighbor exp(-30) terms dropped (~1e-10 effect vs threshold 32).
// R19: verbatim resubmission of the best-measured configuration (R13/R2,
// 170.7us). Rationale: six structural rewrites since (LDS-free kC, crec
// packing, register prefetch, block-regrid, persistent kernel, split-sweep)
// all measured neutral-to-negative; only dispatch-count reduction ever won.
// This pins the best config + repeat-measures its noise band.
//   kA: adj -> bm AND bmT in one pass (per-tile ballots) + features.
//   kB: rowsums -> hsS (= h * 1/rowsum).
//   kC: attention-aggregate + elu + x Wg1/Wo1 -> T (full-i sweep, readlane
//       mask broadcast, no LDS staging).
//   kD: GCN1 aggregate + relu + x W2 -> T2 (full-k sweep, T from L2).
//   kE: final A*T2 + log_softmax / leaky.

// ---------------------------------------------------------------------------
// kA: blocks 0..255: 4 waves x one 64x64 adj tile each -> bm + bmT words.
//     blocks 256..303: feature transform (h, e1, e2, exp packs).
__global__ __launch_bounds__(256) void kA(
    const float* __restrict__ adj0, unsigned int* __restrict__ bm,
    unsigned int* __restrict__ bmT,
    const float* __restrict__ node, const float* __restrict__ uv,
    const float* __restrict__ Wt1, const float* __restrict__ at1,
    const float* __restrict__ Wt2, const float* __restrict__ at2,
    float* __restrict__ hcol, float* __restrict__ pack1, float* __restrict__ pack2) {
  int b = blockIdx.x;
  if (b < 256) {
    int lane = threadIdx.x & 63, w = threadIdx.x >> 6;
    int t = b * 4 + w;                  // 1024 tiles
    int ti = t >> 5, tj = t & 31;       // ti: row-block, tj: col-block
    int row = ti * 64 + lane;
    const float4* ar4 = (const float4*)(adj0 + (size_t)row * 2048 + tj * 64);
    unsigned int rowLo = 0, rowHi = 0, myLo = 0, myHi = 0;
#pragma unroll
    for (int it = 0; it < 16; ++it) {
      float4 v = ar4[it];
      unsigned long long m0 = __ballot(v.x == 1.0f);
      unsigned long long m1 = __ballot(v.y == 1.0f);
      unsigned long long m2 = __ballot(v.z == 1.0f);
      unsigned long long m3 = __ballot(v.w == 1.0f);
      int jb = it * 4;
      if (jb + 0 == lane) { myLo = (unsigned int)m0; myHi = (unsigned int)(m0 >> 32); }
      if (jb + 1 == lane) { myLo = (unsigned int)m1; myHi = (unsigned int)(m1 >> 32); }
      if (jb + 2 == lane) { myLo = (unsigned int)m2; myHi = (unsigned int)(m2 >> 32); }
      if (jb + 3 == lane) { myLo = (unsigned int)m3; myHi = (unsigned int)(m3 >> 32); }
      unsigned int rb = (v.x == 1.0f ? 1u : 0u) | (v.y == 1.0f ? 2u : 0u) |
                        (v.z == 1.0f ? 4u : 0u) | (v.w == 1.0f ? 8u : 0u);
      if (it < 8) rowLo |= rb << (it * 4);
      else rowHi |= rb << ((it - 8) * 4);
    }
    *(uint2*)&bm[(size_t)row * 64 + tj * 2] = make_uint2(rowLo, rowHi);
    int j = tj * 64 + lane;
    *(uint2*)&bmT[(size_t)j * 64 + ti * 2] = make_uint2(myLo, myHi);
    return;
  }
  __shared__ float sW[192];
  __shared__ float sA[12];
  int fb = b - 256;                 // 0..47
  int g = fb / 24;
  int h = (fb / 8) % 3;
  int e = (fb % 8) * 256 + threadIdx.x;
  const float* W = (g ? Wt2 : Wt1) + h * 192;
  const float* A = (g ? at2 : at1) + h * 12;
  const float* x = (g ? uv : node) + e * 32;
  if (threadIdx.x < 192) sW[threadIdx.x] = W[threadIdx.x];
  if (threadIdx.x < 12) sA[threadIdx.x] = A[threadIdx.x];
  __syncthreads();
  float xv[32];
#pragma unroll
  for (int i = 0; i < 32; ++i) xv[i] = x[i];
  float hv[6];
#pragma unroll
  for (int d = 0; d < 6; ++d) hv[d] = 0.f;
#pragma unroll
  for (int i = 0; i < 32; ++i)
#pragma unroll
    for (int d = 0; d < 6; ++d) hv[d] += xv[i] * sW[i * 6 + d];
  float e1 = 0.f, e2 = 0.f;
#pragma unroll
  for (int d = 0; d < 6; ++d) {
    e1 += hv[d] * sA[d];
    e2 += hv[d] * sA[6 + d];
  }
  int c = g * 3 + h;
#pragma unroll
  for (int d = 0; d < 6; ++d) hcol[(c * 6 + d) * 2048 + e] = hv[d];
  pack1[c * 2048 + e] = e1;
  pack1[(6 + c) * 2048 + e] = __expf(e1);
  pack1[(12 + c) * 2048 + e] = __expf(0.2f * e1);
  pack2[c * 2048 + e] = e2;
  pack2[(6 + c) * 2048 + e] = __expf(e2);
  pack2[(12 + c) * 2048 + e] = __expf(0.2f * e2);
}

// ---------------------------------------------------------------------------
// kB: rowsum over j -> hsS[c*6+d][i] = h[i,d]/rowsum(i,c). Block 384
// (wave = comp c), 8 rows per block, lanes sweep j 4-at-a-time.
__global__ __launch_bounds__(384) void kB(
    const unsigned int* __restrict__ bm, const float* __restrict__ pack1,
    const float* __restrict__ pack2, const float* __restrict__ hcol,
    float* __restrict__ hsS) {
  int tid = threadIdx.x;
  int c = tid >> 6, lane = tid & 63;
  int i0 = blockIdx.x * 8;
  const float4* p2_4 = (const float4*)pack2;
  float e1r[8], p1r[8], q1r[8], sum[8];
#pragma unroll
  for (int r = 0; r < 8; ++r) {
    e1r[r] = pack1[c * 2048 + i0 + r];
    p1r[r] = pack1[(6 + c) * 2048 + i0 + r];
    q1r[r] = pack1[(12 + c) * 2048 + i0 + r];
    sum[r] = 0.f;
  }
  int sh = (lane & 7) * 4;
#pragma unroll
  for (int it = 0; it < 8; ++it) {
    int j4 = it * 64 + lane;  // float4 index; covers j = 4*j4 .. +3
    float4 e2 = p2_4[c * 512 + j4];
    float4 p2 = p2_4[(6 + c) * 512 + j4];
    float4 q2 = p2_4[(12 + c) * 512 + j4];
    int wbase = it * 8 + (lane >> 3);
    float abx, aby, abz, abw;
#pragma unroll
    for (int r = 0; r < 8; ++r) {
      unsigned int wd = bm[(i0 + r) * 64 + wbase] >> sh;
      { float e = e1r[r] + e2.x; bool p = e > 0.f;
        abx = (p ? p1r[r] : q1r[r]) * (p ? p2.x : q2.x); }
      { float e = e1r[r] + e2.y; bool p = e > 0.f;
        aby = (p ? p1r[r] : q1r[r]) * (p ? p2.y : q2.y); }
      { float e = e1r[r] + e2.z; bool p = e > 0.f;
        abz = (p ? p1r[r] : q1r[r]) * (p ? p2.z : q2.z); }
      { float e = e1r[r] + e2.w; bool p = e > 0.f;
        abw = (p ? p1r[r] : q1r[r]) * (p ? p2.w : q2.w); }
      float s = ((wd & 1u) ? abx : 0.f) + ((wd & 2u) ? aby : 0.f) +
                ((wd & 4u) ? abz : 0.f) + ((wd & 8u) ? abw : 0.f);
      sum[r] += s;
    }
  }
#pragma unroll
  for (int r = 0; r < 8; ++r) {
#pragma unroll
    for (int off = 32; off > 0; off >>= 1) sum[r] += __shfl_xor(sum[r], off);
  }
  if (lane < 6) {
    int row = c * 6 + lane;
#pragma unroll
    for (int r = 0; r < 8; ++r) {
      float inv = 1.0f / sum[r];
      hsS[row * 2048 + i0 + r] = hcol[row * 2048 + i0 + r] * inv;
    }
  }
}

// ---------------------------------------------------------------------------
// kC: fused attention-aggregate + GCN1 input: for a 4-wide j-tile, full-i
// sweep of hp[j,c*6+d] = sum_i w(i,j,c)*hsS[c*6+d][i]; then elu and
// x Wg1/Wo1 -> T[j][32]. Wave = comp c; lane L owns i = s*64+L; mask words
// held in regs (wj) + broadcast via readlane. Grid 512 (j0 = blk*4).
__global__ __launch_bounds__(384) void kC(
    const unsigned int* __restrict__ bmT, const float* __restrict__ pack1,
    const float* __restrict__ pack2, const float* __restrict__ hsS,
    const float* __restrict__ Wg1, const float* __restrict__ Wo1,
    float* __restrict__ T) {
  __shared__ float sW[576];       // Wg1 (288) then Wo1 (288)
  __shared__ float sHP[4 * 37];
  int tid = threadIdx.x;
  int c = tid >> 6, L = tid & 63;
  int j0 = blockIdx.x * 4;
  if (tid < 288) { sW[tid] = Wg1[tid]; sW[288 + tid] = Wo1[tid]; }
  // per-lane mask words: wj[jj] = word L of column j0+jj (rows L*32..L*32+31)
  int wj[4];
#pragma unroll
  for (int jj = 0; jj < 4; ++jj) wj[jj] = (int)bmT[(size_t)(j0 + jj) * 64 + L];
  // wave-uniform j-side scalars
  float e2v[4], p2v[4], q2v[4];
#pragma unroll
  for (int jj = 0; jj < 4; ++jj) {
    e2v[jj] = pack2[c * 2048 + j0 + jj];
    p2v[jj] = pack2[(6 + c) * 2048 + j0 + jj];
    q2v[jj] = pack2[(12 + c) * 2048 + j0 + jj];
  }
  float acc[4][6];
#pragma unroll
  for (int jj = 0; jj < 4; ++jj)
#pragma unroll
    for (int d = 0; d < 6; ++d) acc[jj][d] = 0.f;

  for (int s = 0; s < 32; ++s) {
    int i = s * 64 + L;
    float e1 = pack1[c * 2048 + i];
    float p1 = pack1[(6 + c) * 2048 + i];
    float q1 = pack1[(12 + c) * 2048 + i];
    float h0 = hsS[(c * 6 + 0) * 2048 + i];
    float h1 = hsS[(c * 6 + 1) * 2048 + i];
    float h2 = hsS[(c * 6 + 2) * 2048 + i];
    float h3 = hsS[(c * 6 + 3) * 2048 + i];
    float h4 = hsS[(c * 6 + 4) * 2048 + i];
    float h5 = hsS[(c * 6 + 5) * 2048 + i];
#pragma unroll
    for (int jj = 0; jj < 4; ++jj) {
      int lo = __builtin_amdgcn_readlane(wj[jj], 2 * s);
      int hi = __builtin_amdgcn_readlane(wj[jj], 2 * s + 1);
      unsigned int wsel = (unsigned int)((L & 32) ? hi : lo);
      float e = e1 + e2v[jj];
      bool pos = e > 0.f;
      float ab = (pos ? p1 : q1) * (pos ? p2v[jj] : q2v[jj]);
      float wgt = ((wsel >> (L & 31)) & 1u) ? ab : 0.f;
      acc[jj][0] += wgt * h0; acc[jj][1] += wgt * h1; acc[jj][2] += wgt * h2;
      acc[jj][3] += wgt * h3; acc[jj][4] += wgt * h4; acc[jj][5] += wgt * h5;
    }
  }
  // butterfly: every lane ends with the full i-sum
#pragma unroll
  for (int jj = 0; jj < 4; ++jj)
#pragma unroll
    for (int d = 0; d < 6; ++d)
#pragma unroll
      for (int off = 32; off > 0; off >>= 1)
        acc[jj][d] += __shfl_xor(acc[jj][d], off);
  if (L == 0) {
#pragma unroll
    for (int jj = 0; jj < 4; ++jj)
#pragma unroll
      for (int d = 0; d < 6; ++d) {
        float x = acc[jj][d];
        sHP[jj * 37 + c * 6 + d] = x > 0.f ? x : __expf(x) - 1.f;  // elu
      }
  }
  __syncthreads();
  if (tid < 128) {
    int j = tid >> 5, col = tid & 31;
    int gat = col >> 4, cp = col & 15;
    const float* Wp = sW + gat * 288;
    const float* hp = sHP + j * 37 + gat * 18;
    float a = 0.f;
#pragma unroll
    for (int r = 0; r < 18; ++r) a += hp[r] * Wp[r * 16 + cp];
    T[(size_t)(j0 + j) * 32 + col] = a;
  }
}

// ---------------------------------------------------------------------------
// kD: fused GCN1-aggregate + GCN2 input: 8 rows per block, full-k sweep of
// Craw[r][col] = sum_k bit(r,k)*T[k][col] (T streamed from L2, no LDS
// staging); then relu(+bias) x Wg2/Wo2 -> T2[r][4]. Grid 256.
__global__ __launch_bounds__(256) void kD(
    const unsigned int* __restrict__ bm, const float* __restrict__ T,
    const float* __restrict__ bg1, const float* __restrict__ bo1,
    const float* __restrict__ Wg2, const float* __restrict__ Wo2,
    float* __restrict__ T2) {
  __shared__ float sC[8 * 32];
  int tid = threadIdx.x;
  int kl = tid & 31, cg = tid >> 5;   // kl: k-lane, cg: float4 col-group
  int r0 = blockIdx.x * 8;
  const float4* T4 = (const float4*)T;
  float4 acc[8];
#pragma unroll
  for (int rr = 0; rr < 8; ++rr) acc[rr] = make_float4(0.f, 0.f, 0.f, 0.f);
  for (int ch = 0; ch < 8; ++ch) {
    // prefetch 8 T values (k = ch*256 + t*32 + kl), 8-deep MLP
    float4 tv[8];
#pragma unroll
    for (int t = 0; t < 8; ++t)
      tv[t] = T4[(size_t)(ch * 256 + t * 32 + kl) * 8 + cg];
#pragma unroll
    for (int rr = 0; rr < 8; ++rr) {
      const unsigned int* wp = &bm[(size_t)(r0 + rr) * 64 + ch * 8];
      uint4 wA = *(const uint4*)wp;        // words t=0..3
      uint4 wB = *(const uint4*)(wp + 4);  // words t=4..7
      float m;
      m = (float)((wA.x >> kl) & 1u);
      acc[rr].x += m * tv[0].x; acc[rr].y += m * tv[0].y;
      acc[rr].z += m * tv[0].z; acc[rr].w += m * tv[0].w;
      m = (float)((wA.y >> kl) & 1u);
      acc[rr].x += m * tv[1].x; acc[rr].y += m * tv[1].y;
      acc[rr].z += m * tv[1].z; acc[rr].w += m * tv[1].w;
      m = (float)((wA.z >> kl) & 1u);
      acc[rr].x += m * tv[2].x; acc[rr].y += m * tv[2].y;
      acc[rr].z += m * tv[2].z; acc[rr].w += m * tv[2].w;
      m = (float)((wA.w >> kl) & 1u);
      acc[rr].x += m * tv[3].x; acc[rr].y += m * tv[3].y;
      acc[rr].z += m * tv[3].z; acc[rr].w += m * tv[3].w;
      m = (float)((wB.x >> kl) & 1u);
      acc[rr].x += m * tv[4].x; acc[rr].y += m * tv[4].y;
      acc[rr].z += m * tv[4].z; acc[rr].w += m * tv[4].w;
      m = (float)((wB.y >> kl) & 1u);
      acc[rr].x += m * tv[5].x; acc[rr].y += m * tv[5].y;
      acc[rr].z += m * tv[5].z; acc[rr].w += m * tv[5].w;
      m = (float)((wB.z >> kl) & 1u);
      acc[rr].x += m * tv[6].x; acc[rr].y += m * tv[6].y;
      acc[rr].z += m * tv[6].z; acc[rr].w += m * tv[6].w;
      m = (float)((wB.w >> kl) & 1u);
      acc[rr].x += m * tv[7].x; acc[rr].y += m * tv[7].y;
      acc[rr].z += m * tv[7].z; acc[rr].w += m * tv[7].w;
    }
  }
  // reduce over the 32 kl-lanes (stays within each 32-lane half-wave)
#pragma unroll
  for (int rr = 0; rr < 8; ++rr) {
#pragma unroll
    for (int m = 16; m > 0; m >>= 1) {
      acc[rr].x += __shfl_xor(acc[rr].x, m);
      acc[rr].y += __shfl_xor(acc[rr].y, m);
      acc[rr].z += __shfl_xor(acc[rr].z, m);
      acc[rr].w += __shfl_xor(acc[rr].w, m);
    }
  }
  if (kl == 0) {
#pragma unroll
    for (int rr = 0; rr < 8; ++rr)
      *(float4*)&sC[rr * 32 + cg * 4] = acc[rr];
  }
  __syncthreads();
  {
    int r = tid >> 5, col = tid & 31;
    int gat = col >> 4, cc = col & 15;
    float x = sC[r * 32 + col] + (gat ? bo1[cc] : bg1[cc]);
    x = x > 0.f ? x : 0.f;  // relu
    float wa = gat ? Wo2[cc * 2 + 0] : Wg2[cc * 2 + 0];
    float wb = gat ? Wo2[cc * 2 + 1] : Wg2[cc * 2 + 1];
    float pa = x * wa, pb = x * wb;
#pragma unroll
    for (int m = 8; m > 0; m >>= 1) {
      pa += __shfl_xor(pa, m);
      pb += __shfl_xor(pb, m);
    }
    if (cc == 0) {
      T2[(size_t)(r0 + r) * 4 + gat * 2 + 0] = pa;
      T2[(size_t)(r0 + r) * 4 + gat * 2 + 1] = pb;
    }
  }
}

// ---------------------------------------------------------------------------
// kE: final out = a0 @ T2 (+bias), log_softmax(axis=1) + leaky(0.01).
// Wave per row, grid 512.
__global__ __launch_bounds__(256) void kE(
    const unsigned int* __restrict__ bm, const float* __restrict__ T2,
    const float* __restrict__ bg2, const float* __restrict__ bo2,
    float* __restrict__ out) {
  int tid = threadIdx.x;
  int lane = tid & 63, w = tid >> 6;
  int r = blockIdx.x * 4 + w;
  const float4* T24 = (const float4*)T2;
  float4 acc = make_float4(0.f, 0.f, 0.f, 0.f);
  int sh = lane & 31;
#pragma unroll 8
  for (int it = 0; it < 32; ++it) {
    int k = it * 64 + lane;
    unsigned int wd = bm[r * 64 + it * 2 + (lane >> 5)];
    float m = (float)((wd >> sh) & 1u);
    float4 t = T24[k];
    acc.x += m * t.x;
    acc.y += m * t.y;
    acc.z += m * t.z;
    acc.w += m * t.w;
  }
#pragma unroll
  for (int off = 32; off > 0; off >>= 1) {
    acc.x += __shfl_down(acc.x, off);
    acc.y += __shfl_down(acc.y, off);
    acc.z += __shfl_down(acc.z, off);
    acc.w += __shfl_down(acc.w, off);
  }
  if (lane == 0) {
    float y0 = acc.x + bg2[0], y1 = acc.y + bg2[1];
    float m = fmaxf(y0, y1);
    float ls = m + logf(__expf(y0 - m) + __expf(y1 - m));
    out[r * 2 + 0] = y0 - ls;
    out[r * 2 + 1] = y1 - ls;
    float o0 = acc.z + bo2[0], o1 = acc.w + bo2[1];
    out[4096 + r * 2 + 0] = o0 > 0.f ? o0 : 0.01f * o0;
    out[4096 + r * 2 + 1] = o1 > 0.f ? o1 : 0.01f * o1;
  }
}

extern "C" void kernel_launch(void* const* d_in, const int* in_sizes, int n_in,
                              void* d_out, int out_size, void* d_ws, size_t ws_size,
                              hipStream_t stream) {
  const float* node = (const float*)d_in[0];
  const float* uv = (const float*)d_in[1];
  const float* adj = (const float*)d_in[2];  // batch 0 = first 2048*2048
  const float* Wt1 = (const float*)d_in[3];
  const float* at1 = (const float*)d_in[4];
  const float* Wt2 = (const float*)d_in[5];
  const float* at2 = (const float*)d_in[6];
  const float* Wg1 = (const float*)d_in[7];
  const float* bg1 = (const float*)d_in[8];
  const float* Wg2 = (const float*)d_in[9];
  const float* bg2 = (const float*)d_in[10];
  const float* Wo1 = (const float*)d_in[11];
  const float* bo1 = (const float*)d_in[12];
  const float* Wo2 = (const float*)d_in[13];
  const float* bo2 = (const float*)d_in[14];
  float* ws = (float*)d_ws;
  float* hcol = ws;                               // 73728
  float* pack1 = ws + 73728;                      // 36864
  float* pack2 = ws + 110592;                     // 36864
  float* hsS = ws + 147456;                       // 73728
  float* T = ws + 221184;                         // 65536
  float* T2 = ws + 286720;                        // 8192
  unsigned int* bm = (unsigned int*)(ws + 294912);   // 131072 u32 = 512 KB
  unsigned int* bmT = (unsigned int*)(ws + 425984);  // 131072 u32 = 512 KB
  float* out = (float*)d_out;

  kA<<<304, 256, 0, stream>>>(adj, bm, bmT, node, uv, Wt1, at1, Wt2, at2,
                              hcol, pack1, pack2);
  kB<<<256, 384, 0, stream>>>(bm, pack1, pack2, hcol, hsS);
  kC<<<512, 384, 0, stream>>>(bmT, pack1, pack2, hsS, Wg1, Wo1, T);
  kD<<<256, 256, 0, stream>>>(bm, T, bg1, bo1, Wg2, Wo2, T2);
  kE<<<512, 256, 0, stream>>>(bm, T2, bg2, bo2, out);
}